// Round 3
// baseline (633.579 us; speedup 1.0000x reference)
//
#include <hip/hip_runtime.h>
#include <cstdint>
#include <cstddef>

#define SEQ_ 4096
#define DIM_ 1280
#define NHEAD_ 20
#define HDIM_ 64
#define FFN_ 5120
#define SEG_ 512
#define QKVN_ 3840

typedef __attribute__((ext_vector_type(8))) short bf16x8;
typedef __attribute__((ext_vector_type(4))) float f32x4;
typedef __attribute__((ext_vector_type(8))) unsigned short us8;
typedef __attribute__((ext_vector_type(4))) unsigned short us4;

__device__ __forceinline__ unsigned short f2b(float f) {
  unsigned int u = __builtin_bit_cast(unsigned int, f);
  u += 0x7fffu + ((u >> 16) & 1u);
  return (unsigned short)(u >> 16);
}

__device__ __forceinline__ void gload_lds16(const void* g, void* l) {
  __builtin_amdgcn_global_load_lds(
      (const __attribute__((address_space(1))) unsigned int*)g,
      (__attribute__((address_space(3))) unsigned int*)l, 16, 0, 0);
}

#define WAITVM(N) asm volatile("s_waitcnt vmcnt(" #N ")" ::: "memory")

// ---------- transpose + f32->bf16: out[C][R] = bf16(in[R][C]) ----------
__global__ __launch_bounds__(256) void transp_bf16_kernel(
    const float* __restrict__ in, unsigned short* __restrict__ out, int R, int C) {
  __shared__ float tile[32][33];
  int c0 = blockIdx.x * 32, r0 = blockIdx.y * 32;
  int tx = threadIdx.x & 31, ty = threadIdx.x >> 5;
#pragma unroll
  for (int i = 0; i < 32; i += 8)
    tile[ty + i][tx] = in[(size_t)(r0 + ty + i) * C + c0 + tx];
  __syncthreads();
#pragma unroll
  for (int i = 0; i < 32; i += 8)
    out[(size_t)(c0 + ty + i) * R + r0 + tx] = f2b(tile[tx][ty + i]);
}

// ---------- layernorm f32 -> bf16 ----------
__global__ __launch_bounds__(256) void ln_kernel(
    const float* __restrict__ in, const float* __restrict__ g,
    const float* __restrict__ b, unsigned short* __restrict__ out) {
  int row = blockIdx.x, tid = threadIdx.x;
  int l = tid & 63, w = tid >> 6;
  const float* x = in + (size_t)row * DIM_;
  float v[5], s = 0.f, s2 = 0.f;
#pragma unroll
  for (int i = 0; i < 5; ++i) {
    v[i] = x[tid + i * 256];
    s += v[i];
    s2 += v[i] * v[i];
  }
#pragma unroll
  for (int off = 1; off < 64; off <<= 1) {
    s += __shfl_xor(s, off);
    s2 += __shfl_xor(s2, off);
  }
  __shared__ float red[8];
  if (l == 0) { red[w * 2] = s; red[w * 2 + 1] = s2; }
  __syncthreads();
  s = red[0] + red[2] + red[4] + red[6];
  s2 = red[1] + red[3] + red[5] + red[7];
  float mu = s * (1.f / DIM_);
  float var = s2 * (1.f / DIM_) - mu * mu;
  float rs = rsqrtf(var + 1e-5f);
#pragma unroll
  for (int i = 0; i < 5; ++i) {
    int c = tid + i * 256;
    out[(size_t)row * DIM_ + c] = f2b((v[i] - mu) * rs * g[c] + b[c]);
  }
}

// ---------- 256x256 GEMM, BK=32, 8 waves, 4-slot LDS pipeline, counted vmcnt ----------
enum { EPI_QKV = 0, EPI_RES = 2, EPI_GELU = 3, EPI_PART = 4 };

template <int EPI>
__global__ __launch_bounds__(512, 2) void gemm256_kernel(
    const unsigned short* __restrict__ A, int lda,
    const unsigned short* __restrict__ Bt, int ldb,
    const float* __restrict__ bias, const float* __restrict__ bias2,
    const float* __restrict__ res,
    void* __restrict__ out0, void* __restrict__ out1, void* __restrict__ out2,
    int M, int N, int K) {
  // per slot: A [kg:4][row:256][8] (16KB) then B [kg:4][row:256][8] (16KB)
  __shared__ char lds[4][32768];
  const int tid = threadIdx.x;
  const int l = tid & 63, w = tid >> 6;
  const int r16 = l & 15, kg4 = l >> 4;
  // XCD-chunked swizzle (per z-plane; nwg always %8==0 here)
  const int nwg = gridDim.x * gridDim.y;
  const int orig = blockIdx.y * gridDim.x + blockIdx.x;
  const int swz = (orig & 7) * (nwg >> 3) + (orig >> 3);
  const int m0 = (swz / gridDim.x) * 256, n0 = (swz % gridDim.x) * 256;
  const int wm = (w >> 2) * 128, wn = (w & 3) * 64;
  // split-K
  A += (size_t)blockIdx.z * K;
  Bt += (size_t)blockIdx.z * K;
  // staging source base addrs: chunk c covers (kg=c>>8, row=c&255)
  const int c0 = tid, c1 = tid + 512;
  const unsigned short* aA0 = A + (size_t)(m0 + (c0 & 255)) * lda + (c0 >> 8) * 8;
  const unsigned short* aA1 = A + (size_t)(m0 + (c1 & 255)) * lda + (c1 >> 8) * 8;
  const unsigned short* aB0 = Bt + (size_t)(n0 + (c0 & 255)) * ldb + (c0 >> 8) * 8;
  const unsigned short* aB1 = Bt + (size_t)(n0 + (c1 & 255)) * ldb + (c1 >> 8) * 8;

  f32x4 acc[8][4] = {};
  const int nt = K >> 5;

#define STAGE(slot, kt_)                                                  \
  do {                                                                    \
    const int kb = (kt_) * 32;                                            \
    char* db = &lds[slot][0] + (w * 64) * 16;                             \
    gload_lds16(aA0 + kb, db);                                            \
    gload_lds16(aA1 + kb, db + 512 * 16);                                 \
    gload_lds16(aB0 + kb, db + 16384);                                    \
    gload_lds16(aB1 + kb, db + 16384 + 512 * 16);                         \
  } while (0)

  // prologue: slots 0,1,2 in flight (12 loads/wave)
  STAGE(0, 0);
  STAGE(1, 1);
  STAGE(2, 2);

#pragma unroll 1
  for (int t = 0; t < nt; ++t) {
    const char* sA = &lds[t & 3][0];
    if (t + 3 < nt) STAGE((t + 3) & 3, t + 3);
    const int rem = nt - 1 - t;
    if (rem >= 3) WAITVM(12);
    else if (rem == 2) WAITVM(8);
    else if (rem == 1) WAITVM(4);
    else WAITVM(0);
    __builtin_amdgcn_s_barrier();
    __builtin_amdgcn_sched_barrier(0);
    bf16x8 af[8], bfv[4];
#pragma unroll
    for (int mi = 0; mi < 8; ++mi)
      af[mi] = *(const bf16x8*)(sA + ((kg4 << 8) + wm + mi * 16 + r16) * 16);
#pragma unroll
    for (int ni = 0; ni < 2; ++ni)
      bfv[ni] = *(const bf16x8*)(sA + 16384 + ((kg4 << 8) + wn + ni * 16 + r16) * 16);
    __builtin_amdgcn_s_setprio(1);
#pragma unroll
    for (int mi = 0; mi < 8; ++mi)
#pragma unroll
      for (int ni = 0; ni < 2; ++ni)
        acc[mi][ni] = __builtin_amdgcn_mfma_f32_16x16x32_bf16(af[mi], bfv[ni], acc[mi][ni], 0, 0, 0);
    __builtin_amdgcn_s_setprio(0);
#pragma unroll
    for (int ni = 2; ni < 4; ++ni)
      bfv[ni] = *(const bf16x8*)(sA + 16384 + ((kg4 << 8) + wn + ni * 16 + r16) * 16);
    __builtin_amdgcn_s_setprio(1);
#pragma unroll
    for (int mi = 0; mi < 8; ++mi)
#pragma unroll
      for (int ni = 2; ni < 4; ++ni)
        acc[mi][ni] = __builtin_amdgcn_mfma_f32_16x16x32_bf16(af[mi], bfv[ni], acc[mi][ni], 0, 0, 0);
    __builtin_amdgcn_s_setprio(0);
    __builtin_amdgcn_sched_barrier(0);
    __builtin_amdgcn_s_barrier();
    __builtin_amdgcn_sched_barrier(0);
  }
#undef STAGE

  const int rg = (l >> 4) * 4;
#pragma unroll
  for (int mi = 0; mi < 8; ++mi) {
#pragma unroll
    for (int ni = 0; ni < 4; ++ni) {
      int row = m0 + wm + mi * 16 + rg;
      int col = n0 + wn + ni * 16 + r16;
      f32x4 v = acc[mi][ni];
      if constexpr (EPI == EPI_QKV) {
        if (col < DIM_) {  // Q (+bq)
          unsigned short* O = (unsigned short*)out0;
          float bb = bias[col];
#pragma unroll
          for (int j = 0; j < 4; ++j) O[(size_t)(row + j) * DIM_ + col] = f2b(v[j] + bb);
        } else if (col < 2 * DIM_) {  // K (no bias)
          unsigned short* O = (unsigned short*)out1;
          int cc = col - DIM_;
#pragma unroll
          for (int j = 0; j < 4; ++j) O[(size_t)(row + j) * DIM_ + cc] = f2b(v[j]);
        } else {  // V (+bv), transposed store -> Vt[d][s]
          unsigned short* O = (unsigned short*)out2;
          int cc = col - 2 * DIM_;
          float bb = bias2[cc];
          us4 pk;
#pragma unroll
          for (int j = 0; j < 4; ++j) pk[j] = f2b(v[j] + bb);
          *(us4*)(O + (size_t)cc * SEQ_ + row) = pk;
        }
      } else if constexpr (EPI == EPI_RES) {
        float* O = (float*)out0;
        float bb = bias[col];
#pragma unroll
        for (int j = 0; j < 4; ++j)
          O[(size_t)(row + j) * N + col] = v[j] + bb + res[(size_t)(row + j) * N + col];
      } else if constexpr (EPI == EPI_GELU) {
        unsigned short* O = (unsigned short*)out0;
        float bb = bias[col];
#pragma unroll
        for (int j = 0; j < 4; ++j) {
          float t = v[j] + bb;
          t = 0.5f * t * (1.f + erff(t * 0.70710678118f));
          O[(size_t)(row + j) * N + col] = f2b(t);
        }
      } else {  // EPI_PART
        float* O = (float*)out0 + (size_t)blockIdx.z * M * N;
#pragma unroll
        for (int j = 0; j < 4; ++j) O[(size_t)(row + j) * N + col] = v[j];
      }
    }
  }
}

// ---------- split-K reduce: out = p0 + p1 + bias + res ----------
__global__ __launch_bounds__(256) void reduce_kernel(
    const float* __restrict__ part, const float* __restrict__ bias,
    const float* __restrict__ res, float* __restrict__ out) {
  const size_t MN = (size_t)SEQ_ * DIM_;
  for (size_t i = blockIdx.x * 256 + threadIdx.x; i * 4 < MN; i += (size_t)gridDim.x * 256) {
    size_t e = i * 4;
    f32x4 a = *(const f32x4*)(part + e);
    f32x4 b = *(const f32x4*)(part + MN + e);
    f32x4 r = *(const f32x4*)(res + e);
    f32x4 bb = *(const f32x4*)(bias + (int)(e % DIM_));
    f32x4 o = a + b + r + bb;
    *(f32x4*)(out + e) = o;
  }
}

// ---------- attention: per (head, seg, 64-row q chunk) ----------
__global__ __launch_bounds__(256) void attn_kernel(
    const unsigned short* __restrict__ Q, const unsigned short* __restrict__ Kb,
    const unsigned short* __restrict__ Vt, unsigned short* __restrict__ O) {
  __shared__ float S[64][512];
  int tid = threadIdx.x;
  int l = tid & 63, w = tid >> 6;
  int orig = blockIdx.x;
  int b = (orig & 7) * (gridDim.x >> 3) + (orig >> 3);
  int qc = b & 7, seg = (b >> 3) & 7, hh = b >> 6;
  int r16 = l & 15, kg = l >> 4, rg = (l >> 4) * 4;
  int qrow0 = seg * SEG_ + qc * 64 + w * 16;
  bf16x8 aq[2];
#pragma unroll
  for (int ks = 0; ks < 2; ++ks)
    aq[ks] = *(const bf16x8*)(Q + (size_t)(qrow0 + r16) * DIM_ + hh * HDIM_ + ks * 32 + kg * 8);
#pragma unroll 4
  for (int kc = 0; kc < 32; ++kc) {
    f32x4 acc = {};
#pragma unroll
    for (int ks = 0; ks < 2; ++ks) {
      bf16x8 bk = *(const bf16x8*)(Kb + (size_t)(seg * SEG_ + kc * 16 + r16) * DIM_ +
                                   hh * HDIM_ + ks * 32 + kg * 8);
      acc = __builtin_amdgcn_mfma_f32_16x16x32_bf16(aq[ks], bk, acc, 0, 0, 0);
    }
#pragma unroll
    for (int j = 0; j < 4; ++j)
      S[w * 16 + rg + j][kc * 16 + r16] = acc[j] * 0.125f;
  }
#pragma unroll 2
  for (int r = 0; r < 16; ++r) {
    float* Sr = &S[w * 16 + r][0];
    f32x4 v0 = *(const f32x4*)(Sr + l * 8);
    f32x4 v1 = *(const f32x4*)(Sr + l * 8 + 4);
    float m = fmaxf(fmaxf(fmaxf(v0[0], v0[1]), fmaxf(v0[2], v0[3])),
                    fmaxf(fmaxf(v1[0], v1[1]), fmaxf(v1[2], v1[3])));
#pragma unroll
    for (int off = 1; off < 64; off <<= 1) m = fmaxf(m, __shfl_xor(m, off));
    float ev[8];
    ev[0] = v0[0]; ev[1] = v0[1]; ev[2] = v0[2]; ev[3] = v0[3];
    ev[4] = v1[0]; ev[5] = v1[1]; ev[6] = v1[2]; ev[7] = v1[3];
    float sum = 0.f;
#pragma unroll
    for (int j = 0; j < 8; ++j) { ev[j] = __expf(ev[j] - m); sum += ev[j]; }
#pragma unroll
    for (int off = 1; off < 64; off <<= 1) sum += __shfl_xor(sum, off);
    float inv = 1.f / sum;
    us8 pk;
#pragma unroll
    for (int j = 0; j < 8; ++j) pk[j] = f2b(ev[j] * inv);
    *(us8*)((unsigned short*)Sr + ((l ^ (r & 7)) * 8)) = pk;
  }
  f32x4 oacc[4] = {};
  const unsigned short* Pr = (const unsigned short*)&S[w * 16 + r16][0];
  int rowx = r16 & 7;
#pragma unroll 2
  for (int ks = 0; ks < 16; ++ks) {
    int chunk = (ks * 4 + kg) ^ rowx;
    bf16x8 pa = *(const bf16x8*)(Pr + chunk * 8);
#pragma unroll
    for (int df = 0; df < 4; ++df) {
      bf16x8 bv = *(const bf16x8*)(Vt + (size_t)(hh * HDIM_ + df * 16 + r16) * SEQ_ +
                                   seg * SEG_ + ks * 32 + kg * 8);
      oacc[df] = __builtin_amdgcn_mfma_f32_16x16x32_bf16(pa, bv, oacc[df], 0, 0, 0);
    }
  }
#pragma unroll
  for (int df = 0; df < 4; ++df)
#pragma unroll
    for (int j = 0; j < 4; ++j)
      O[(size_t)(qrow0 + rg + j) * DIM_ + hh * HDIM_ + df * 16 + r16] = f2b(oacc[df][j]);
}

extern "C" void kernel_launch(void* const* d_in, const int* in_sizes, int n_in,
                              void* d_out, int out_size, void* d_ws, size_t ws_size,
                              hipStream_t stream) {
  (void)in_sizes; (void)n_in; (void)out_size; (void)ws_size;
  const float* hidden = (const float*)d_in[0];
  const float* Wq = (const float*)d_in[2];
  const float* bq = (const float*)d_in[3];
  const float* Wk = (const float*)d_in[4];
  const float* Wv = (const float*)d_in[5];
  const float* bv = (const float*)d_in[6];
  const float* Wo = (const float*)d_in[7];
  const float* bo = (const float*)d_in[8];
  const float* g1 = (const float*)d_in[9];
  const float* b1 = (const float*)d_in[10];
  const float* Wf1 = (const float*)d_in[11];
  const float* bf1 = (const float*)d_in[12];
  const float* Wf2 = (const float*)d_in[13];
  const float* bf2 = (const float*)d_in[14];
  const float* g2 = (const float*)d_in[15];
  const float* b2 = (const float*)d_in[16];

  char* p = (char*)d_ws;
  auto alloc = [&](size_t bytes) {
    char* r = p;
    p += (bytes + 255) & ~(size_t)255;
    return r;
  };
  unsigned short* xln   = (unsigned short*)alloc((size_t)SEQ_ * DIM_ * 2);
  unsigned short* Wqkvt = (unsigned short*)alloc((size_t)DIM_ * QKVN_ * 2);
  unsigned short* Wot   = (unsigned short*)alloc((size_t)DIM_ * DIM_ * 2);
  unsigned short* Wf1t  = (unsigned short*)alloc((size_t)DIM_ * FFN_ * 2);
  unsigned short* Wf2t  = (unsigned short*)alloc((size_t)DIM_ * FFN_ * 2);
  unsigned short* Qb    = (unsigned short*)alloc((size_t)SEQ_ * DIM_ * 2);
  unsigned short* Kbf   = (unsigned short*)alloc((size_t)SEQ_ * DIM_ * 2);
  unsigned short* Vtb   = (unsigned short*)alloc((size_t)SEQ_ * DIM_ * 2);
  unsigned short* attnb = (unsigned short*)alloc((size_t)SEQ_ * DIM_ * 2);
  float*          hbuf  = (float*)alloc((size_t)SEQ_ * DIM_ * 4);
  unsigned short* ybuf  = (unsigned short*)alloc((size_t)SEQ_ * DIM_ * 2);
  unsigned short* gbuf  = (unsigned short*)alloc((size_t)SEQ_ * FFN_ * 2);
  // split-K partials alias Qb..attnb (dead after Wo GEMM): 2*SEQ*DIM f32 == 4*SEQ*DIM bf16
  float* part = (float*)Qb;

  transp_bf16_kernel<<<dim3(DIM_ / 32, DIM_ / 32), 256, 0, stream>>>(Wq, Wqkvt, DIM_, DIM_);
  transp_bf16_kernel<<<dim3(DIM_ / 32, DIM_ / 32), 256, 0, stream>>>(Wk, Wqkvt + (size_t)DIM_ * DIM_, DIM_, DIM_);
  transp_bf16_kernel<<<dim3(DIM_ / 32, DIM_ / 32), 256, 0, stream>>>(Wv, Wqkvt + (size_t)2 * DIM_ * DIM_, DIM_, DIM_);
  transp_bf16_kernel<<<dim3(DIM_ / 32, DIM_ / 32), 256, 0, stream>>>(Wo, Wot, DIM_, DIM_);
  transp_bf16_kernel<<<dim3(FFN_ / 32, DIM_ / 32), 256, 0, stream>>>(Wf1, Wf1t, DIM_, FFN_);
  transp_bf16_kernel<<<dim3(DIM_ / 32, FFN_ / 32), 256, 0, stream>>>(Wf2, Wf2t, FFN_, DIM_);
  ln_kernel<<<SEQ_, 256, 0, stream>>>(hidden, g1, b1, xln);
  // fused QKV projection: N=3840 -> Q, K, V(transposed)
  gemm256_kernel<EPI_QKV><<<dim3(QKVN_ / 256, SEQ_ / 256), 512, 0, stream>>>(
      xln, DIM_, Wqkvt, DIM_, bq, bv, nullptr, Qb, Kbf, Vtb, SEQ_, QKVN_, DIM_);
  attn_kernel<<<NHEAD_ * 8 * 8, 256, 0, stream>>>(Qb, Kbf, Vtb, attnb);
  // output proj + residual -> hbuf (f32)
  gemm256_kernel<EPI_RES><<<dim3(DIM_ / 256, SEQ_ / 256), 512, 0, stream>>>(
      attnb, DIM_, Wot, DIM_, bo, nullptr, hidden, hbuf, nullptr, nullptr, SEQ_, DIM_, DIM_);
  ln_kernel<<<SEQ_, 256, 0, stream>>>(hbuf, g2, b2, ybuf);
  // FFN1 + GELU
  gemm256_kernel<EPI_GELU><<<dim3(FFN_ / 256, SEQ_ / 256), 512, 0, stream>>>(
      ybuf, DIM_, Wf1t, DIM_, bf1, nullptr, nullptr, gbuf, nullptr, nullptr, SEQ_, FFN_, DIM_);
  // FFN2 split-K=2 -> f32 partials, reduce(+bias+residual) -> d_out
  gemm256_kernel<EPI_PART><<<dim3(DIM_ / 256, SEQ_ / 256, 2), 512, 0, stream>>>(
      gbuf, FFN_, Wf2t, FFN_, nullptr, nullptr, nullptr, part, nullptr, nullptr, SEQ_, DIM_, FFN_ / 2);
  reduce_kernel<<<2048, 256, 0, stream>>>(part, bf2, hbuf, (float*)d_out);
}

// Round 4
// 623.876 us; speedup vs baseline: 1.0156x; 1.0156x over previous
//
#include <hip/hip_runtime.h>
#include <cstdint>
#include <cstddef>

#define SEQ_ 4096
#define DIM_ 1280
#define NHEAD_ 20
#define HDIM_ 64
#define FFN_ 5120
#define SEG_ 512
#define QKVN_ 3840

typedef __attribute__((ext_vector_type(8))) short bf16x8;
typedef __attribute__((ext_vector_type(4))) float f32x4;
typedef __attribute__((ext_vector_type(8))) unsigned short us8;
typedef __attribute__((ext_vector_type(4))) unsigned short us4;

__device__ __forceinline__ unsigned short f2b(float f) {
  unsigned int u = __builtin_bit_cast(unsigned int, f);
  u += 0x7fffu + ((u >> 16) & 1u);
  return (unsigned short)(u >> 16);
}

__device__ __forceinline__ void gload_lds16(const void* g, void* l) {
  __builtin_amdgcn_global_load_lds(
      (const __attribute__((address_space(1))) unsigned int*)g,
      (__attribute__((address_space(3))) unsigned int*)l, 16, 0, 0);
}

#define WAITVM(N) asm volatile("s_waitcnt vmcnt(" #N ")" ::: "memory")

// ---------- transpose + f32->bf16: out[C][R] = bf16(in[R][C]) ----------
__global__ __launch_bounds__(256) void transp_bf16_kernel(
    const float* __restrict__ in, unsigned short* __restrict__ out, int R, int C) {
  __shared__ float tile[32][33];
  int c0 = blockIdx.x * 32, r0 = blockIdx.y * 32;
  int tx = threadIdx.x & 31, ty = threadIdx.x >> 5;
#pragma unroll
  for (int i = 0; i < 32; i += 8)
    tile[ty + i][tx] = in[(size_t)(r0 + ty + i) * C + c0 + tx];
  __syncthreads();
#pragma unroll
  for (int i = 0; i < 32; i += 8)
    out[(size_t)(c0 + ty + i) * R + r0 + tx] = f2b(tile[tx][ty + i]);
}

// ---------- layernorm f32 -> bf16 ----------
__global__ __launch_bounds__(256) void ln_kernel(
    const float* __restrict__ in, const float* __restrict__ g,
    const float* __restrict__ b, unsigned short* __restrict__ out) {
  int row = blockIdx.x, tid = threadIdx.x;
  int l = tid & 63, w = tid >> 6;
  const float* x = in + (size_t)row * DIM_;
  float v[5], s = 0.f, s2 = 0.f;
#pragma unroll
  for (int i = 0; i < 5; ++i) {
    v[i] = x[tid + i * 256];
    s += v[i];
    s2 += v[i] * v[i];
  }
#pragma unroll
  for (int off = 1; off < 64; off <<= 1) {
    s += __shfl_xor(s, off);
    s2 += __shfl_xor(s2, off);
  }
  __shared__ float red[8];
  if (l == 0) { red[w * 2] = s; red[w * 2 + 1] = s2; }
  __syncthreads();
  s = red[0] + red[2] + red[4] + red[6];
  s2 = red[1] + red[3] + red[5] + red[7];
  float mu = s * (1.f / DIM_);
  float var = s2 * (1.f / DIM_) - mu * mu;
  float rs = rsqrtf(var + 1e-5f);
#pragma unroll
  for (int i = 0; i < 5; ++i) {
    int c = tid + i * 256;
    out[(size_t)row * DIM_ + c] = f2b((v[i] - mu) * rs * g[c] + b[c]);
  }
}

// ---------- 256x256 GEMM, BK=32, 8 waves, 3-slot LDS rotation ----------
// steady state: <=8 outstanding global_load_lds per wave (64/CU);
// one counted vmcnt(4) + one s_barrier per K-step; vmcnt never 0 except tail.
enum { EPI_QKV = 0, EPI_RES = 2, EPI_GELU = 3, EPI_PART = 4 };

template <int EPI>
__global__ __launch_bounds__(512, 2) void gemm256_kernel(
    const unsigned short* __restrict__ A, int lda,
    const unsigned short* __restrict__ Bt, int ldb,
    const float* __restrict__ bias, const float* __restrict__ bias2,
    const float* __restrict__ res,
    void* __restrict__ out0, void* __restrict__ out1, void* __restrict__ out2,
    int M, int N, int K) {
  // per slot 32 KiB: A [kg:4][row:256][8] (16KB) then B (16KB)
  __shared__ char lds[3][32768];
  const int tid = threadIdx.x;
  const int l = tid & 63, w = tid >> 6;
  const int r16 = l & 15, kg4 = l >> 4;
  const int nwg = gridDim.x * gridDim.y;
  const int orig = blockIdx.y * gridDim.x + blockIdx.x;
  const int swz = (orig & 7) * (nwg >> 3) + (orig >> 3);
  const int m0 = (swz / gridDim.x) * 256, n0 = (swz % gridDim.x) * 256;
  const int wm = (w >> 2) * 128, wn = (w & 3) * 64;
  A += (size_t)blockIdx.z * K;
  Bt += (size_t)blockIdx.z * K;
  // staging source addrs: chunk c=(kg,row): kg=c>>8, row=c&255
  const int c0 = tid, c1 = tid + 512;
  const unsigned short* aA0 = A + (size_t)(m0 + (c0 & 255)) * lda + (c0 >> 8) * 8;
  const unsigned short* aA1 = A + (size_t)(m0 + (c1 & 255)) * lda + (c1 >> 8) * 8;
  const unsigned short* aB0 = Bt + (size_t)(n0 + (c0 & 255)) * ldb + (c0 >> 8) * 8;
  const unsigned short* aB1 = Bt + (size_t)(n0 + (c1 & 255)) * ldb + (c1 >> 8) * 8;

  f32x4 acc[8][4] = {};
  const int nt = K >> 5;

#define STAGE(slot, kt_)                                      \
  do {                                                        \
    const int kb = (kt_) * 32;                                \
    char* db = &lds[slot][0] + (w * 64) * 16;                 \
    gload_lds16(aA0 + kb, db);                                \
    gload_lds16(aA1 + kb, db + 8192);                         \
    gload_lds16(aB0 + kb, db + 16384);                        \
    gload_lds16(aB1 + kb, db + 16384 + 8192);                 \
  } while (0)

  // prologue: slots 0,1 in flight (8 loads/wave)
  STAGE(0, 0);
  STAGE(1, 1);
  WAITVM(4);  // slot 0 landed (own loads); barrier publishes to all waves
  __builtin_amdgcn_s_barrier();

  int sl = 0;
#pragma unroll 1
  for (int t = 0; t < nt; ++t) {
    if (t + 2 < nt) {
      int s2 = sl + 2; if (s2 >= 3) s2 -= 3;
      STAGE(s2, t + 2);  // slot (t+2)%3 last read in iter t-1 (pre-barrier) -> safe
    }
    const char* sA = &lds[sl][0];
    bf16x8 af[8], bfv[4];
#pragma unroll
    for (int mi = 0; mi < 8; ++mi)
      af[mi] = *(const bf16x8*)(sA + ((kg4 << 8) + wm + mi * 16 + r16) * 16);
#pragma unroll
    for (int ni = 0; ni < 4; ++ni)
      bfv[ni] = *(const bf16x8*)(sA + 16384 + ((kg4 << 8) + wn + ni * 16 + r16) * 16);
    __builtin_amdgcn_s_setprio(1);
#pragma unroll
    for (int mi = 0; mi < 8; ++mi)
#pragma unroll
      for (int ni = 0; ni < 4; ++ni)
        acc[mi][ni] = __builtin_amdgcn_mfma_f32_16x16x32_bf16(af[mi], bfv[ni], acc[mi][ni], 0, 0, 0);
    __builtin_amdgcn_s_setprio(0);
    if (t + 1 < nt) {
      if (t + 2 < nt) WAITVM(4);  // retire slot t+1's loads; t+2's 4 stay in flight
      else WAITVM(0);             // tail only
      __builtin_amdgcn_s_barrier();
    }
    ++sl; if (sl == 3) sl = 0;
  }
#undef STAGE

  const int rg = (l >> 4) * 4;
#pragma unroll
  for (int mi = 0; mi < 8; ++mi) {
#pragma unroll
    for (int ni = 0; ni < 4; ++ni) {
      int row = m0 + wm + mi * 16 + rg;
      int col = n0 + wn + ni * 16 + r16;
      f32x4 v = acc[mi][ni];
      if constexpr (EPI == EPI_QKV) {
        if (col < DIM_) {  // Q (+bq)
          unsigned short* O = (unsigned short*)out0;
          float bb = bias[col];
#pragma unroll
          for (int j = 0; j < 4; ++j) O[(size_t)(row + j) * DIM_ + col] = f2b(v[j] + bb);
        } else if (col < 2 * DIM_) {  // K (no bias)
          unsigned short* O = (unsigned short*)out1;
          int cc = col - DIM_;
#pragma unroll
          for (int j = 0; j < 4; ++j) O[(size_t)(row + j) * DIM_ + cc] = f2b(v[j]);
        } else {  // V (+bv), transposed store -> Vt[d][s]
          unsigned short* O = (unsigned short*)out2;
          int cc = col - 2 * DIM_;
          float bb = bias2[cc];
          us4 pk;
#pragma unroll
          for (int j = 0; j < 4; ++j) pk[j] = f2b(v[j] + bb);
          *(us4*)(O + (size_t)cc * SEQ_ + row) = pk;
        }
      } else if constexpr (EPI == EPI_RES) {
        float* O = (float*)out0;
        float bb = bias[col];
#pragma unroll
        for (int j = 0; j < 4; ++j)
          O[(size_t)(row + j) * N + col] = v[j] + bb + res[(size_t)(row + j) * N + col];
      } else if constexpr (EPI == EPI_GELU) {
        unsigned short* O = (unsigned short*)out0;
        float bb = bias[col];
#pragma unroll
        for (int j = 0; j < 4; ++j) {
          float t = v[j] + bb;
          t = 0.5f * t * (1.f + erff(t * 0.70710678118f));
          O[(size_t)(row + j) * N + col] = f2b(t);
        }
      } else {  // EPI_PART
        float* O = (float*)out0 + (size_t)blockIdx.z * M * N;
#pragma unroll
        for (int j = 0; j < 4; ++j) O[(size_t)(row + j) * N + col] = v[j];
      }
    }
  }
}

// ---------- split-K reduce: out = p0 + p1 + bias + res ----------
__global__ __launch_bounds__(256) void reduce_kernel(
    const float* __restrict__ part, const float* __restrict__ bias,
    const float* __restrict__ res, float* __restrict__ out) {
  const size_t MN = (size_t)SEQ_ * DIM_;
  for (size_t i = blockIdx.x * 256 + threadIdx.x; i * 4 < MN; i += (size_t)gridDim.x * 256) {
    size_t e = i * 4;
    f32x4 a = *(const f32x4*)(part + e);
    f32x4 b = *(const f32x4*)(part + MN + e);
    f32x4 r = *(const f32x4*)(res + e);
    f32x4 bb = *(const f32x4*)(bias + (int)(e % DIM_));
    f32x4 o = a + b + r + bb;
    *(f32x4*)(out + e) = o;
  }
}

// ---------- attention: per (head, seg, 64-row q chunk) ----------
__global__ __launch_bounds__(256) void attn_kernel(
    const unsigned short* __restrict__ Q, const unsigned short* __restrict__ Kb,
    const unsigned short* __restrict__ Vt, unsigned short* __restrict__ O) {
  __shared__ float S[64][512];
  int tid = threadIdx.x;
  int l = tid & 63, w = tid >> 6;
  int orig = blockIdx.x;
  int b = (orig & 7) * (gridDim.x >> 3) + (orig >> 3);
  int qc = b & 7, seg = (b >> 3) & 7, hh = b >> 6;
  int r16 = l & 15, kg = l >> 4, rg = (l >> 4) * 4;
  int qrow0 = seg * SEG_ + qc * 64 + w * 16;
  bf16x8 aq[2];
#pragma unroll
  for (int ks = 0; ks < 2; ++ks)
    aq[ks] = *(const bf16x8*)(Q + (size_t)(qrow0 + r16) * DIM_ + hh * HDIM_ + ks * 32 + kg * 8);
#pragma unroll 4
  for (int kc = 0; kc < 32; ++kc) {
    f32x4 acc = {};
#pragma unroll
    for (int ks = 0; ks < 2; ++ks) {
      bf16x8 bk = *(const bf16x8*)(Kb + (size_t)(seg * SEG_ + kc * 16 + r16) * DIM_ +
                                   hh * HDIM_ + ks * 32 + kg * 8);
      acc = __builtin_amdgcn_mfma_f32_16x16x32_bf16(aq[ks], bk, acc, 0, 0, 0);
    }
#pragma unroll
    for (int j = 0; j < 4; ++j)
      S[w * 16 + rg + j][kc * 16 + r16] = acc[j] * 0.125f;
  }
#pragma unroll 2
  for (int r = 0; r < 16; ++r) {
    float* Sr = &S[w * 16 + r][0];
    f32x4 v0 = *(const f32x4*)(Sr + l * 8);
    f32x4 v1 = *(const f32x4*)(Sr + l * 8 + 4);
    float m = fmaxf(fmaxf(fmaxf(v0[0], v0[1]), fmaxf(v0[2], v0[3])),
                    fmaxf(fmaxf(v1[0], v1[1]), fmaxf(v1[2], v1[3])));
#pragma unroll
    for (int off = 1; off < 64; off <<= 1) m = fmaxf(m, __shfl_xor(m, off));
    float ev[8];
    ev[0] = v0[0]; ev[1] = v0[1]; ev[2] = v0[2]; ev[3] = v0[3];
    ev[4] = v1[0]; ev[5] = v1[1]; ev[6] = v1[2]; ev[7] = v1[3];
    float sum = 0.f;
#pragma unroll
    for (int j = 0; j < 8; ++j) { ev[j] = __expf(ev[j] - m); sum += ev[j]; }
#pragma unroll
    for (int off = 1; off < 64; off <<= 1) sum += __shfl_xor(sum, off);
    float inv = 1.f / sum;
    us8 pk;
#pragma unroll
    for (int j = 0; j < 8; ++j) pk[j] = f2b(ev[j] * inv);
    *(us8*)((unsigned short*)Sr + ((l ^ (r & 7)) * 8)) = pk;
  }
  f32x4 oacc[4] = {};
  const unsigned short* Pr = (const unsigned short*)&S[w * 16 + r16][0];
  int rowx = r16 & 7;
#pragma unroll 2
  for (int ks = 0; ks < 16; ++ks) {
    int chunk = (ks * 4 + kg) ^ rowx;
    bf16x8 pa = *(const bf16x8*)(Pr + chunk * 8);
#pragma unroll
    for (int df = 0; df < 4; ++df) {
      bf16x8 bv = *(const bf16x8*)(Vt + (size_t)(hh * HDIM_ + df * 16 + r16) * SEQ_ +
                                   seg * SEG_ + ks * 32 + kg * 8);
      oacc[df] = __builtin_amdgcn_mfma_f32_16x16x32_bf16(pa, bv, oacc[df], 0, 0, 0);
    }
  }
#pragma unroll
  for (int df = 0; df < 4; ++df)
#pragma unroll
    for (int j = 0; j < 4; ++j)
      O[(size_t)(qrow0 + rg + j) * DIM_ + hh * HDIM_ + df * 16 + r16] = f2b(oacc[df][j]);
}

extern "C" void kernel_launch(void* const* d_in, const int* in_sizes, int n_in,
                              void* d_out, int out_size, void* d_ws, size_t ws_size,
                              hipStream_t stream) {
  (void)in_sizes; (void)n_in; (void)out_size; (void)ws_size;
  const float* hidden = (const float*)d_in[0];
  const float* Wq = (const float*)d_in[2];
  const float* bq = (const float*)d_in[3];
  const float* Wk = (const float*)d_in[4];
  const float* Wv = (const float*)d_in[5];
  const float* bv = (const float*)d_in[6];
  const float* Wo = (const float*)d_in[7];
  const float* bo = (const float*)d_in[8];
  const float* g1 = (const float*)d_in[9];
  const float* b1 = (const float*)d_in[10];
  const float* Wf1 = (const float*)d_in[11];
  const float* bf1 = (const float*)d_in[12];
  const float* Wf2 = (const float*)d_in[13];
  const float* bf2 = (const float*)d_in[14];
  const float* g2 = (const float*)d_in[15];
  const float* b2 = (const float*)d_in[16];

  char* p = (char*)d_ws;
  auto alloc = [&](size_t bytes) {
    char* r = p;
    p += (bytes + 255) & ~(size_t)255;
    return r;
  };
  unsigned short* xln   = (unsigned short*)alloc((size_t)SEQ_ * DIM_ * 2);
  unsigned short* Wqkvt = (unsigned short*)alloc((size_t)DIM_ * QKVN_ * 2);
  unsigned short* Wot   = (unsigned short*)alloc((size_t)DIM_ * DIM_ * 2);
  unsigned short* Wf1t  = (unsigned short*)alloc((size_t)DIM_ * FFN_ * 2);
  unsigned short* Wf2t  = (unsigned short*)alloc((size_t)DIM_ * FFN_ * 2);
  unsigned short* Qb    = (unsigned short*)alloc((size_t)SEQ_ * DIM_ * 2);
  unsigned short* Kbf   = (unsigned short*)alloc((size_t)SEQ_ * DIM_ * 2);
  unsigned short* Vtb   = (unsigned short*)alloc((size_t)SEQ_ * DIM_ * 2);
  unsigned short* attnb = (unsigned short*)alloc((size_t)SEQ_ * DIM_ * 2);
  float*          hbuf  = (float*)alloc((size_t)SEQ_ * DIM_ * 4);
  unsigned short* ybuf  = (unsigned short*)alloc((size_t)SEQ_ * DIM_ * 2);
  unsigned short* gbuf  = (unsigned short*)alloc((size_t)SEQ_ * FFN_ * 2);
  // split-K partials alias Qb..attnb (dead after Wo GEMM): 2*SEQ*DIM f32 == 4*SEQ*DIM bf16
  float* part = (float*)Qb;

  transp_bf16_kernel<<<dim3(DIM_ / 32, DIM_ / 32), 256, 0, stream>>>(Wq, Wqkvt, DIM_, DIM_);
  transp_bf16_kernel<<<dim3(DIM_ / 32, DIM_ / 32), 256, 0, stream>>>(Wk, Wqkvt + (size_t)DIM_ * DIM_, DIM_, DIM_);
  transp_bf16_kernel<<<dim3(DIM_ / 32, DIM_ / 32), 256, 0, stream>>>(Wv, Wqkvt + (size_t)2 * DIM_ * DIM_, DIM_, DIM_);
  transp_bf16_kernel<<<dim3(DIM_ / 32, DIM_ / 32), 256, 0, stream>>>(Wo, Wot, DIM_, DIM_);
  transp_bf16_kernel<<<dim3(FFN_ / 32, DIM_ / 32), 256, 0, stream>>>(Wf1, Wf1t, DIM_, FFN_);
  transp_bf16_kernel<<<dim3(DIM_ / 32, FFN_ / 32), 256, 0, stream>>>(Wf2, Wf2t, FFN_, DIM_);
  ln_kernel<<<SEQ_, 256, 0, stream>>>(hidden, g1, b1, xln);
  // fused QKV projection: N=3840 -> Q, K, V(transposed)
  gemm256_kernel<EPI_QKV><<<dim3(QKVN_ / 256, SEQ_ / 256), 512, 0, stream>>>(
      xln, DIM_, Wqkvt, DIM_, bq, bv, nullptr, Qb, Kbf, Vtb, SEQ_, QKVN_, DIM_);
  attn_kernel<<<NHEAD_ * 8 * 8, 256, 0, stream>>>(Qb, Kbf, Vtb, attnb);
  // output proj + residual -> hbuf (f32)
  gemm256_kernel<EPI_RES><<<dim3(DIM_ / 256, SEQ_ / 256), 512, 0, stream>>>(
      attnb, DIM_, Wot, DIM_, bo, nullptr, hidden, hbuf, nullptr, nullptr, SEQ_, DIM_, DIM_);
  ln_kernel<<<SEQ_, 256, 0, stream>>>(hbuf, g2, b2, ybuf);
  // FFN1 + GELU
  gemm256_kernel<EPI_GELU><<<dim3(FFN_ / 256, SEQ_ / 256), 512, 0, stream>>>(
      ybuf, DIM_, Wf1t, DIM_, bf1, nullptr, nullptr, gbuf, nullptr, nullptr, SEQ_, FFN_, DIM_);
  // FFN2 split-K=2 -> f32 partials, reduce(+bias+residual) -> d_out
  gemm256_kernel<EPI_PART><<<dim3(DIM_ / 256, SEQ_ / 256, 2), 512, 0, stream>>>(
      gbuf, FFN_, Wf2t, FFN_, nullptr, nullptr, nullptr, part, nullptr, nullptr, SEQ_, DIM_, FFN_ / 2);
  reduce_kernel<<<2048, 256, 0, stream>>>(part, bf2, hbuf, (float*)d_out);
}

// Round 5
// 548.447 us; speedup vs baseline: 1.1552x; 1.1375x over previous
//
#include <hip/hip_runtime.h>
#include <cstdint>
#include <cstddef>

#define SEQ_ 4096
#define DIM_ 1280
#define NHEAD_ 20
#define HDIM_ 64
#define FFN_ 5120
#define SEG_ 512
#define QKVN_ 3840

typedef __attribute__((ext_vector_type(8))) short bf16x8;
typedef __attribute__((ext_vector_type(4))) float f32x4;
typedef __attribute__((ext_vector_type(8))) unsigned short us8;
typedef __attribute__((ext_vector_type(4))) unsigned short us4;

__device__ __forceinline__ unsigned short f2b(float f) {
  unsigned int u = __builtin_bit_cast(unsigned int, f);
  u += 0x7fffu + ((u >> 16) & 1u);
  return (unsigned short)(u >> 16);
}

__device__ __forceinline__ void gload_lds16(const void* g, void* l) {
  __builtin_amdgcn_global_load_lds(
      (const __attribute__((address_space(1))) unsigned int*)g,
      (__attribute__((address_space(3))) unsigned int*)l, 16, 0, 0);
}

#define WAITVM(N) asm volatile("s_waitcnt vmcnt(" #N ")" ::: "memory")

// ---------- transpose + f32->bf16: out[C][R] = bf16(in[R][C]) ----------
__global__ __launch_bounds__(256) void transp_bf16_kernel(
    const float* __restrict__ in, unsigned short* __restrict__ out, int R, int C) {
  __shared__ float tile[32][33];
  int c0 = blockIdx.x * 32, r0 = blockIdx.y * 32;
  int tx = threadIdx.x & 31, ty = threadIdx.x >> 5;
#pragma unroll
  for (int i = 0; i < 32; i += 8)
    tile[ty + i][tx] = in[(size_t)(r0 + ty + i) * C + c0 + tx];
  __syncthreads();
#pragma unroll
  for (int i = 0; i < 32; i += 8)
    out[(size_t)(c0 + ty + i) * R + r0 + tx] = f2b(tile[tx][ty + i]);
}

// ---------- layernorm f32 -> bf16 ----------
__global__ __launch_bounds__(256) void ln_kernel(
    const float* __restrict__ in, const float* __restrict__ g,
    const float* __restrict__ b, unsigned short* __restrict__ out) {
  int row = blockIdx.x, tid = threadIdx.x;
  int l = tid & 63, w = tid >> 6;
  const float* x = in + (size_t)row * DIM_;
  float v[5], s = 0.f, s2 = 0.f;
#pragma unroll
  for (int i = 0; i < 5; ++i) {
    v[i] = x[tid + i * 256];
    s += v[i];
    s2 += v[i] * v[i];
  }
#pragma unroll
  for (int off = 1; off < 64; off <<= 1) {
    s += __shfl_xor(s, off);
    s2 += __shfl_xor(s2, off);
  }
  __shared__ float red[8];
  if (l == 0) { red[w * 2] = s; red[w * 2 + 1] = s2; }
  __syncthreads();
  s = red[0] + red[2] + red[4] + red[6];
  s2 = red[1] + red[3] + red[5] + red[7];
  float mu = s * (1.f / DIM_);
  float var = s2 * (1.f / DIM_) - mu * mu;
  float rs = rsqrtf(var + 1e-5f);
#pragma unroll
  for (int i = 0; i < 5; ++i) {
    int c = tid + i * 256;
    out[(size_t)row * DIM_ + c] = f2b((v[i] - mu) * rs * g[c] + b[c]);
  }
}

// ---------- 256x256 GEMM, BK=64, 8 waves, 2-phase dbuf (T3 minimum recipe) ----------
// LDS per buffer: A [row:256][kc:8][8bf16] 32KB @0, B same @32768. Coalesced
// staging: chunk c = row*8+kc -> consecutive 8 lanes read one row's 128B.
enum { EPI_QKV = 0, EPI_RES = 2, EPI_GELU = 3, EPI_PART = 4 };

template <int EPI>
__global__ __launch_bounds__(512, 2) void gemm256_kernel(
    const unsigned short* __restrict__ A, int lda,
    const unsigned short* __restrict__ Bt, int ldb,
    const float* __restrict__ bias, const float* __restrict__ bias2,
    const float* __restrict__ res,
    void* __restrict__ out0, void* __restrict__ out1, void* __restrict__ out2,
    int M, int N, int Ksub) {
  __shared__ char lds[2][65536];
  const int tid = threadIdx.x;
  const int l = tid & 63, w = tid >> 6;
  const int r16 = l & 15, kg4 = l >> 4;
  const int nwg = gridDim.x * gridDim.y;
  const int orig = blockIdx.y * gridDim.x + blockIdx.x;
  const int swz = (orig & 7) * (nwg >> 3) + (orig >> 3);
  const int m0 = (swz / gridDim.x) * 256, n0 = (swz % gridDim.x) * 256;
  const int wm = (w >> 2) * 128, wn = (w & 3) * 64;
  A += (size_t)blockIdx.z * Ksub;
  Bt += (size_t)blockIdx.z * Ksub;
  // coalesced staging base: lane covers (row = w*8 + l/8 [+ g*64], kc = l&7)
  const unsigned short* aA = A + (size_t)(m0 + w * 8 + (l >> 3)) * lda + (l & 7) * 8;
  const unsigned short* aB = Bt + (size_t)(n0 + w * 8 + (l >> 3)) * ldb + (l & 7) * 8;

  f32x4 acc[8][4] = {};
  const int nt = Ksub >> 6;

#define STAGE(b, kt_)                                                     \
  do {                                                                    \
    const size_t kb = (size_t)(kt_) * 64;                                 \
    char* dA = &lds[b][0] + (w * 64) * 16;                                \
    char* dB = dA + 32768;                                                \
    _Pragma("unroll") for (int g = 0; g < 4; ++g) {                       \
      gload_lds16(aA + (size_t)(g * 64) * lda + kb, dA + g * 8192);       \
      gload_lds16(aB + (size_t)(g * 64) * ldb + kb, dB + g * 8192);       \
    }                                                                     \
  } while (0)

  STAGE(0, 0);
  WAITVM(0);
  __builtin_amdgcn_s_barrier();

#pragma unroll 1
  for (int t = 0; t < nt; ++t) {
    if (t + 1 < nt) STAGE((t + 1) & 1, t + 1);
    __builtin_amdgcn_sched_barrier(0);
    const char* sA = &lds[t & 1][0];
    const char* sB = sA + 32768;
#pragma unroll
    for (int kk = 0; kk < 2; ++kk) {
      bf16x8 af[8], bfv[4];
#pragma unroll
      for (int mi = 0; mi < 8; ++mi)
        af[mi] = *(const bf16x8*)(sA + ((wm + mi * 16 + r16) * 8 + kk * 4 + kg4) * 16);
#pragma unroll
      for (int ni = 0; ni < 4; ++ni)
        bfv[ni] = *(const bf16x8*)(sB + ((wn + ni * 16 + r16) * 8 + kk * 4 + kg4) * 16);
      __builtin_amdgcn_s_setprio(1);
#pragma unroll
      for (int mi = 0; mi < 8; ++mi)
#pragma unroll
        for (int ni = 0; ni < 4; ++ni)
          acc[mi][ni] = __builtin_amdgcn_mfma_f32_16x16x32_bf16(af[mi], bfv[ni], acc[mi][ni], 0, 0, 0);
      __builtin_amdgcn_s_setprio(0);
    }
    WAITVM(0);
    __builtin_amdgcn_s_barrier();
  }
#undef STAGE

  const int rg = (l >> 4) * 4;
#pragma unroll
  for (int mi = 0; mi < 8; ++mi) {
#pragma unroll
    for (int ni = 0; ni < 4; ++ni) {
      int row = m0 + wm + mi * 16 + rg;
      int col = n0 + wn + ni * 16 + r16;
      f32x4 v = acc[mi][ni];
      if constexpr (EPI == EPI_QKV) {
        if (col < DIM_) {  // Q (+bq)
          unsigned short* O = (unsigned short*)out0;
          float bb = bias[col];
#pragma unroll
          for (int j = 0; j < 4; ++j) O[(size_t)(row + j) * DIM_ + col] = f2b(v[j] + bb);
        } else if (col < 2 * DIM_) {  // K (no bias)
          unsigned short* O = (unsigned short*)out1;
          int cc = col - DIM_;
#pragma unroll
          for (int j = 0; j < 4; ++j) O[(size_t)(row + j) * DIM_ + cc] = f2b(v[j]);
        } else {  // V (+bv), transposed store -> Vt[d][s]
          unsigned short* O = (unsigned short*)out2;
          int cc = col - 2 * DIM_;
          float bb = bias2[cc];
          us4 pk;
#pragma unroll
          for (int j = 0; j < 4; ++j) pk[j] = f2b(v[j] + bb);
          *(us4*)(O + (size_t)cc * SEQ_ + row) = pk;
        }
      } else if constexpr (EPI == EPI_RES) {
        float* O = (float*)out0;
        float bb = bias[col];
#pragma unroll
        for (int j = 0; j < 4; ++j)
          O[(size_t)(row + j) * N + col] = v[j] + bb + res[(size_t)(row + j) * N + col];
      } else if constexpr (EPI == EPI_GELU) {
        unsigned short* O = (unsigned short*)out0;
        float bb = bias[col];
#pragma unroll
        for (int j = 0; j < 4; ++j) {
          float t = v[j] + bb;
          t = 0.5f * t * (1.f + erff(t * 0.70710678118f));
          O[(size_t)(row + j) * N + col] = f2b(t);
        }
      } else {  // EPI_PART
        float* O = (float*)out0 + (size_t)blockIdx.z * M * N;
#pragma unroll
        for (int j = 0; j < 4; ++j) O[(size_t)(row + j) * N + col] = v[j];
      }
    }
  }
}

// ---------- split-K reduce: out = p0 + p1 + bias + res ----------
__global__ __launch_bounds__(256) void reduce_kernel(
    const float* __restrict__ part, const float* __restrict__ bias,
    const float* __restrict__ res, float* __restrict__ out) {
  const size_t MN = (size_t)SEQ_ * DIM_;
  for (size_t i = blockIdx.x * 256 + threadIdx.x; i * 4 < MN; i += (size_t)gridDim.x * 256) {
    size_t e = i * 4;
    f32x4 a = *(const f32x4*)(part + e);
    f32x4 b = *(const f32x4*)(part + MN + e);
    f32x4 r = *(const f32x4*)(res + e);
    f32x4 bb = *(const f32x4*)(bias + (int)(e % DIM_));
    f32x4 o = a + b + r + bb;
    *(f32x4*)(out + e) = o;
  }
}

// ---------- attention: per (head, seg, 64-row q chunk) ----------
__global__ __launch_bounds__(256) void attn_kernel(
    const unsigned short* __restrict__ Q, const unsigned short* __restrict__ Kb,
    const unsigned short* __restrict__ Vt, unsigned short* __restrict__ O) {
  __shared__ float S[64][512];
  int tid = threadIdx.x;
  int l = tid & 63, w = tid >> 6;
  int orig = blockIdx.x;
  int b = (orig & 7) * (gridDim.x >> 3) + (orig >> 3);
  int qc = b & 7, seg = (b >> 3) & 7, hh = b >> 6;
  int r16 = l & 15, kg = l >> 4, rg = (l >> 4) * 4;
  int qrow0 = seg * SEG_ + qc * 64 + w * 16;
  bf16x8 aq[2];
#pragma unroll
  for (int ks = 0; ks < 2; ++ks)
    aq[ks] = *(const bf16x8*)(Q + (size_t)(qrow0 + r16) * DIM_ + hh * HDIM_ + ks * 32 + kg * 8);
#pragma unroll 4
  for (int kc = 0; kc < 32; ++kc) {
    f32x4 acc = {};
#pragma unroll
    for (int ks = 0; ks < 2; ++ks) {
      bf16x8 bk = *(const bf16x8*)(Kb + (size_t)(seg * SEG_ + kc * 16 + r16) * DIM_ +
                                   hh * HDIM_ + ks * 32 + kg * 8);
      acc = __builtin_amdgcn_mfma_f32_16x16x32_bf16(aq[ks], bk, acc, 0, 0, 0);
    }
#pragma unroll
    for (int j = 0; j < 4; ++j)
      S[w * 16 + rg + j][kc * 16 + r16] = acc[j] * 0.125f;
  }
#pragma unroll 2
  for (int r = 0; r < 16; ++r) {
    float* Sr = &S[w * 16 + r][0];
    f32x4 v0 = *(const f32x4*)(Sr + l * 8);
    f32x4 v1 = *(const f32x4*)(Sr + l * 8 + 4);
    float m = fmaxf(fmaxf(fmaxf(v0[0], v0[1]), fmaxf(v0[2], v0[3])),
                    fmaxf(fmaxf(v1[0], v1[1]), fmaxf(v1[2], v1[3])));
#pragma unroll
    for (int off = 1; off < 64; off <<= 1) m = fmaxf(m, __shfl_xor(m, off));
    float ev[8];
    ev[0] = v0[0]; ev[1] = v0[1]; ev[2] = v0[2]; ev[3] = v0[3];
    ev[4] = v1[0]; ev[5] = v1[1]; ev[6] = v1[2]; ev[7] = v1[3];
    float sum = 0.f;
#pragma unroll
    for (int j = 0; j < 8; ++j) { ev[j] = __expf(ev[j] - m); sum += ev[j]; }
#pragma unroll
    for (int off = 1; off < 64; off <<= 1) sum += __shfl_xor(sum, off);
    float inv = 1.f / sum;
    us8 pk;
#pragma unroll
    for (int j = 0; j < 8; ++j) pk[j] = f2b(ev[j] * inv);
    *(us8*)((unsigned short*)Sr + ((l ^ (r & 7)) * 8)) = pk;
  }
  f32x4 oacc[4] = {};
  const unsigned short* Pr = (const unsigned short*)&S[w * 16 + r16][0];
  int rowx = r16 & 7;
#pragma unroll 2
  for (int ks = 0; ks < 16; ++ks) {
    int chunk = (ks * 4 + kg) ^ rowx;
    bf16x8 pa = *(const bf16x8*)(Pr + chunk * 8);
#pragma unroll
    for (int df = 0; df < 4; ++df) {
      bf16x8 bv = *(const bf16x8*)(Vt + (size_t)(hh * HDIM_ + df * 16 + r16) * SEQ_ +
                                   seg * SEG_ + ks * 32 + kg * 8);
      oacc[df] = __builtin_amdgcn_mfma_f32_16x16x32_bf16(pa, bv, oacc[df], 0, 0, 0);
    }
  }
#pragma unroll
  for (int df = 0; df < 4; ++df)
#pragma unroll
    for (int j = 0; j < 4; ++j)
      O[(size_t)(qrow0 + rg + j) * DIM_ + hh * HDIM_ + df * 16 + r16] = f2b(oacc[df][j]);
}

extern "C" void kernel_launch(void* const* d_in, const int* in_sizes, int n_in,
                              void* d_out, int out_size, void* d_ws, size_t ws_size,
                              hipStream_t stream) {
  (void)in_sizes; (void)n_in; (void)out_size; (void)ws_size;
  const float* hidden = (const float*)d_in[0];
  const float* Wq = (const float*)d_in[2];
  const float* bq = (const float*)d_in[3];
  const float* Wk = (const float*)d_in[4];
  const float* Wv = (const float*)d_in[5];
  const float* bv = (const float*)d_in[6];
  const float* Wo = (const float*)d_in[7];
  const float* bo = (const float*)d_in[8];
  const float* g1 = (const float*)d_in[9];
  const float* b1 = (const float*)d_in[10];
  const float* Wf1 = (const float*)d_in[11];
  const float* bf1 = (const float*)d_in[12];
  const float* Wf2 = (const float*)d_in[13];
  const float* bf2 = (const float*)d_in[14];
  const float* g2 = (const float*)d_in[15];
  const float* b2 = (const float*)d_in[16];

  char* p = (char*)d_ws;
  auto alloc = [&](size_t bytes) {
    char* r = p;
    p += (bytes + 255) & ~(size_t)255;
    return r;
  };
  unsigned short* xln   = (unsigned short*)alloc((size_t)SEQ_ * DIM_ * 2);
  unsigned short* Wqkvt = (unsigned short*)alloc((size_t)DIM_ * QKVN_ * 2);
  unsigned short* Wot   = (unsigned short*)alloc((size_t)DIM_ * DIM_ * 2);
  unsigned short* Wf1t  = (unsigned short*)alloc((size_t)DIM_ * FFN_ * 2);
  unsigned short* Wf2t  = (unsigned short*)alloc((size_t)DIM_ * FFN_ * 2);
  unsigned short* Qb    = (unsigned short*)alloc((size_t)SEQ_ * DIM_ * 2);
  unsigned short* Kbf   = (unsigned short*)alloc((size_t)SEQ_ * DIM_ * 2);
  unsigned short* Vtb   = (unsigned short*)alloc((size_t)SEQ_ * DIM_ * 2);
  unsigned short* attnb = (unsigned short*)alloc((size_t)SEQ_ * DIM_ * 2);
  float*          hbuf  = (float*)alloc((size_t)SEQ_ * DIM_ * 4);
  unsigned short* ybuf  = (unsigned short*)alloc((size_t)SEQ_ * DIM_ * 2);
  unsigned short* gbuf  = (unsigned short*)alloc((size_t)SEQ_ * FFN_ * 2);
  // split-K partials alias Qb..attnb (dead after Wo GEMM): 2*SEQ*DIM f32 == 4*SEQ*DIM bf16
  float* part = (float*)Qb;

  transp_bf16_kernel<<<dim3(DIM_ / 32, DIM_ / 32), 256, 0, stream>>>(Wq, Wqkvt, DIM_, DIM_);
  transp_bf16_kernel<<<dim3(DIM_ / 32, DIM_ / 32), 256, 0, stream>>>(Wk, Wqkvt + (size_t)DIM_ * DIM_, DIM_, DIM_);
  transp_bf16_kernel<<<dim3(DIM_ / 32, DIM_ / 32), 256, 0, stream>>>(Wv, Wqkvt + (size_t)2 * DIM_ * DIM_, DIM_, DIM_);
  transp_bf16_kernel<<<dim3(DIM_ / 32, DIM_ / 32), 256, 0, stream>>>(Wo, Wot, DIM_, DIM_);
  transp_bf16_kernel<<<dim3(FFN_ / 32, DIM_ / 32), 256, 0, stream>>>(Wf1, Wf1t, DIM_, FFN_);
  transp_bf16_kernel<<<dim3(DIM_ / 32, FFN_ / 32), 256, 0, stream>>>(Wf2, Wf2t, FFN_, DIM_);
  ln_kernel<<<SEQ_, 256, 0, stream>>>(hidden, g1, b1, xln);
  // fused QKV projection: N=3840 -> Q, K, V(transposed)
  gemm256_kernel<EPI_QKV><<<dim3(QKVN_ / 256, SEQ_ / 256), 512, 0, stream>>>(
      xln, DIM_, Wqkvt, DIM_, bq, bv, nullptr, Qb, Kbf, Vtb, SEQ_, QKVN_, DIM_);
  attn_kernel<<<NHEAD_ * 8 * 8, 256, 0, stream>>>(Qb, Kbf, Vtb, attnb);
  // output proj + residual -> hbuf (f32)
  gemm256_kernel<EPI_RES><<<dim3(DIM_ / 256, SEQ_ / 256), 512, 0, stream>>>(
      attnb, DIM_, Wot, DIM_, bo, nullptr, hidden, hbuf, nullptr, nullptr, SEQ_, DIM_, DIM_);
  ln_kernel<<<SEQ_, 256, 0, stream>>>(hbuf, g2, b2, ybuf);
  // FFN1 + GELU
  gemm256_kernel<EPI_GELU><<<dim3(FFN_ / 256, SEQ_ / 256), 512, 0, stream>>>(
      ybuf, DIM_, Wf1t, DIM_, bf1, nullptr, nullptr, gbuf, nullptr, nullptr, SEQ_, FFN_, DIM_);
  // FFN2 split-K=2 -> f32 partials, reduce(+bias+residual) -> d_out
  gemm256_kernel<EPI_PART><<<dim3(DIM_ / 256, SEQ_ / 256, 2), 512, 0, stream>>>(
      gbuf, FFN_, Wf2t, FFN_, nullptr, nullptr, nullptr, part, nullptr, nullptr, SEQ_, DIM_, FFN_ / 2);
  reduce_kernel<<<2048, 256, 0, stream>>>(part, bf2, hbuf, (float*)d_out);
}

// Round 6
// 508.575 us; speedup vs baseline: 1.2458x; 1.0784x over previous
//
#include <hip/hip_runtime.h>
#include <cstdint>
#include <cstddef>

#define SEQ_ 4096
#define DIM_ 1280
#define NHEAD_ 20
#define HDIM_ 64
#define FFN_ 5120
#define SEG_ 512
#define QKVN_ 3840

typedef __attribute__((ext_vector_type(8))) short bf16x8;
typedef __attribute__((ext_vector_type(4))) float f32x4;
typedef __attribute__((ext_vector_type(8))) unsigned short us8;
typedef __attribute__((ext_vector_type(4))) unsigned short us4;

__device__ __forceinline__ unsigned short f2b(float f) {
  unsigned int u = __builtin_bit_cast(unsigned int, f);
  u += 0x7fffu + ((u >> 16) & 1u);
  return (unsigned short)(u >> 16);
}

__device__ __forceinline__ void gload_lds16(const void* g, void* l) {
  __builtin_amdgcn_global_load_lds(
      (const __attribute__((address_space(1))) unsigned int*)g,
      (__attribute__((address_space(3))) unsigned int*)l, 16, 0, 0);
}

#define WAITVM(N) asm volatile("s_waitcnt vmcnt(" #N ")" ::: "memory")

// ---------- transpose + f32->bf16: out[C][R] = bf16(in[R][C]) ----------
__global__ __launch_bounds__(256) void transp_bf16_kernel(
    const float* __restrict__ in, unsigned short* __restrict__ out, int R, int C) {
  __shared__ float tile[32][33];
  int c0 = blockIdx.x * 32, r0 = blockIdx.y * 32;
  int tx = threadIdx.x & 31, ty = threadIdx.x >> 5;
#pragma unroll
  for (int i = 0; i < 32; i += 8)
    tile[ty + i][tx] = in[(size_t)(r0 + ty + i) * C + c0 + tx];
  __syncthreads();
#pragma unroll
  for (int i = 0; i < 32; i += 8)
    out[(size_t)(c0 + ty + i) * R + r0 + tx] = f2b(tile[tx][ty + i]);
}

// ---------- layernorm f32 -> bf16 ----------
__global__ __launch_bounds__(256) void ln_kernel(
    const float* __restrict__ in, const float* __restrict__ g,
    const float* __restrict__ b, unsigned short* __restrict__ out) {
  int row = blockIdx.x, tid = threadIdx.x;
  int l = tid & 63, w = tid >> 6;
  const float* x = in + (size_t)row * DIM_;
  float v[5], s = 0.f, s2 = 0.f;
#pragma unroll
  for (int i = 0; i < 5; ++i) {
    v[i] = x[tid + i * 256];
    s += v[i];
    s2 += v[i] * v[i];
  }
#pragma unroll
  for (int off = 1; off < 64; off <<= 1) {
    s += __shfl_xor(s, off);
    s2 += __shfl_xor(s2, off);
  }
  __shared__ float red[8];
  if (l == 0) { red[w * 2] = s; red[w * 2 + 1] = s2; }
  __syncthreads();
  s = red[0] + red[2] + red[4] + red[6];
  s2 = red[1] + red[3] + red[5] + red[7];
  float mu = s * (1.f / DIM_);
  float var = s2 * (1.f / DIM_) - mu * mu;
  float rs = rsqrtf(var + 1e-5f);
#pragma unroll
  for (int i = 0; i < 5; ++i) {
    int c = tid + i * 256;
    out[(size_t)row * DIM_ + c] = f2b((v[i] - mu) * rs * g[c] + b[c]);
  }
}

// ---------- 256x256 GEMM: BK=32, 4-slot LDS ring, 4 phases/K-tile,
// counted vmcnt(8) once per K-tile (T3+T4), XOR bank swizzle (T2, rule #21),
// setprio around MFMA clusters (T5). 8 waves (2M x 4N), 512 threads. ----------
// LDS slot (32KB): A [row:256][kc:4][16B] @0, B same @16384.
// Swizzle: element (row, kc) stored at phys kc^((row>>1)&3) via pre-swizzled
// global source; ds_read applies the same XOR. Ring distance 3: tile j+3
// staged (1 gload/thread/phase) into slot (j-1)%4 while computing tile j.
enum { EPI_QKV = 0, EPI_RES = 2, EPI_GELU = 3, EPI_PART = 4 };

template <int EPI>
__global__ __launch_bounds__(512, 2) void gemm256_kernel(
    const unsigned short* __restrict__ A, int lda,
    const unsigned short* __restrict__ Bt, int ldb,
    const float* __restrict__ bias, const float* __restrict__ bias2,
    const float* __restrict__ res,
    void* __restrict__ out0, void* __restrict__ out1, void* __restrict__ out2,
    int M, int N, int Ksub) {
  __shared__ char lds[4][32768];
  const int tid = threadIdx.x;
  const int l = tid & 63, w = tid >> 6;
  const int r16 = l & 15, kg4 = l >> 4;
  const int nwg = gridDim.x * gridDim.y;
  const int orig = blockIdx.y * gridDim.x + blockIdx.x;
  const int swz = (orig & 7) * (nwg >> 3) + (orig >> 3);
  const int m0 = (swz / gridDim.x) * 256, n0 = (swz % gridDim.x) * 256;
  const int wm = (w >> 2) * 128, wn = (w & 3) * 64;
  A += (size_t)blockIdx.z * Ksub;
  Bt += (size_t)blockIdx.z * Ksub;

  // staging sources (pre-swizzled k-chunk; rows 0-127 pass0, 128-255 pass1)
  const int srow0 = tid >> 2, srow1 = 128 + (tid >> 2);
  const int kcp = tid & 3;
  const int klog0 = kcp ^ ((srow0 >> 1) & 3);
  const int klog1 = kcp ^ ((srow1 >> 1) & 3);
  const unsigned short* sA0 = A + (size_t)(m0 + srow0) * lda + klog0 * 8;
  const unsigned short* sA1 = A + (size_t)(m0 + srow1) * lda + klog1 * 8;
  const unsigned short* sB0 = Bt + (size_t)(n0 + srow0) * ldb + klog0 * 8;
  const unsigned short* sB1 = Bt + (size_t)(n0 + srow1) * ldb + klog1 * 8;

  // fragment read offsets (swizzled), constant across K-tiles
  int aoff[8], boff[4];
#pragma unroll
  for (int mi = 0; mi < 8; ++mi) {
    int r = wm + mi * 16 + r16;
    aoff[mi] = r * 64 + ((kg4 ^ ((r >> 1) & 3)) << 4);
  }
#pragma unroll
  for (int ni = 0; ni < 4; ++ni) {
    int r = wn + ni * 16 + r16;
    boff[ni] = 16384 + r * 64 + ((kg4 ^ ((r >> 1) & 3)) << 4);
  }

  f32x4 acc[8][4] = {};
  const int nt = Ksub >> 5;

  // prologue: stage K-tiles 0,1,2 (12 loads/thread), publish tile 0
#pragma unroll
  for (int p = 0; p < 3; ++p) {
    char* d = &lds[p][0] + w * 1024;
    const int ko = p * 32;
    gload_lds16(sA0 + ko, d);
    gload_lds16(sA1 + ko, d + 8192);
    gload_lds16(sB0 + ko, d + 16384);
    gload_lds16(sB1 + ko, d + 16384 + 8192);
  }
  WAITVM(8);
  __builtin_amdgcn_s_barrier();

#define PHASE(q, STAGE_STMT)                                                   \
  do {                                                                         \
    bf16x8 a0 = *(const bf16x8*)(sl + aoff[2 * (q)]);                          \
    bf16x8 a1 = *(const bf16x8*)(sl + aoff[2 * (q) + 1]);                      \
    STAGE_STMT;                                                                \
    __builtin_amdgcn_s_barrier();                                              \
    __builtin_amdgcn_s_setprio(1);                                             \
    _Pragma("unroll") for (int ni = 0; ni < 4; ++ni) {                         \
      acc[2 * (q)][ni] = __builtin_amdgcn_mfma_f32_16x16x32_bf16(              \
          a0, bfv[ni], acc[2 * (q)][ni], 0, 0, 0);                             \
      acc[2 * (q) + 1][ni] = __builtin_amdgcn_mfma_f32_16x16x32_bf16(          \
          a1, bfv[ni], acc[2 * (q) + 1][ni], 0, 0, 0);                         \
    }                                                                          \
    __builtin_amdgcn_s_setprio(0);                                             \
  } while (0)

#pragma unroll 1
  for (int j = 0; j < nt; ++j) {
    const char* sl = &lds[j & 3][0];
    char* dst = &lds[(j + 3) & 3][0] + w * 1024;
    const int koff = (j + 3) * 32;
    const bool st = (j + 3) < nt;
    bf16x8 bfv[4];
#pragma unroll
    for (int ni = 0; ni < 4; ++ni) bfv[ni] = *(const bf16x8*)(sl + boff[ni]);
    PHASE(0, if (st) gload_lds16(sA0 + koff, dst));
    __builtin_amdgcn_s_barrier();
    PHASE(1, if (st) gload_lds16(sA1 + koff, dst + 8192));
    __builtin_amdgcn_s_barrier();
    PHASE(2, if (st) gload_lds16(sB0 + koff, dst + 16384));
    __builtin_amdgcn_s_barrier();
    PHASE(3, if (st) gload_lds16(sB1 + koff, dst + 16384 + 8192));
    // K-tile boundary: retire tile j+1's loads; keep j+2/j+3 in flight
    if (j + 1 < nt) {
      if (j + 3 < nt) WAITVM(8);
      else if (j + 2 < nt) WAITVM(4);
      else WAITVM(0);
    }
    __builtin_amdgcn_s_barrier();
  }
#undef PHASE

  const int rg = kg4 * 4;
#pragma unroll
  for (int mi = 0; mi < 8; ++mi) {
#pragma unroll
    for (int ni = 0; ni < 4; ++ni) {
      int row = m0 + wm + mi * 16 + rg;
      int col = n0 + wn + ni * 16 + r16;
      f32x4 v = acc[mi][ni];
      if constexpr (EPI == EPI_QKV) {
        if (col < DIM_) {  // Q (+bq)
          unsigned short* O = (unsigned short*)out0;
          float bb = bias[col];
#pragma unroll
          for (int j = 0; j < 4; ++j) O[(size_t)(row + j) * DIM_ + col] = f2b(v[j] + bb);
        } else if (col < 2 * DIM_) {  // K (no bias)
          unsigned short* O = (unsigned short*)out1;
          int cc = col - DIM_;
#pragma unroll
          for (int j = 0; j < 4; ++j) O[(size_t)(row + j) * DIM_ + cc] = f2b(v[j]);
        } else {  // V (+bv), transposed store -> Vt[d][s]
          unsigned short* O = (unsigned short*)out2;
          int cc = col - 2 * DIM_;
          float bb = bias2[cc];
          us4 pk;
#pragma unroll
          for (int j = 0; j < 4; ++j) pk[j] = f2b(v[j] + bb);
          *(us4*)(O + (size_t)cc * SEQ_ + row) = pk;
        }
      } else if constexpr (EPI == EPI_RES) {
        float* O = (float*)out0;
        float bb = bias[col];
#pragma unroll
        for (int j = 0; j < 4; ++j)
          O[(size_t)(row + j) * N + col] = v[j] + bb + res[(size_t)(row + j) * N + col];
      } else if constexpr (EPI == EPI_GELU) {
        unsigned short* O = (unsigned short*)out0;
        float bb = bias[col];
#pragma unroll
        for (int j = 0; j < 4; ++j) {
          float t = v[j] + bb;
          t = 0.5f * t * (1.f + erff(t * 0.70710678118f));
          O[(size_t)(row + j) * N + col] = f2b(t);
        }
      } else {  // EPI_PART
        float* O = (float*)out0 + (size_t)blockIdx.z * M * N;
#pragma unroll
        for (int j = 0; j < 4; ++j) O[(size_t)(row + j) * N + col] = v[j];
      }
    }
  }
}

// ---------- split-K reduce: out = p0 + p1 + bias + res ----------
__global__ __launch_bounds__(256) void reduce_kernel(
    const float* __restrict__ part, const float* __restrict__ bias,
    const float* __restrict__ res, float* __restrict__ out) {
  const size_t MN = (size_t)SEQ_ * DIM_;
  for (size_t i = blockIdx.x * 256 + threadIdx.x; i * 4 < MN; i += (size_t)gridDim.x * 256) {
    size_t e = i * 4;
    f32x4 a = *(const f32x4*)(part + e);
    f32x4 b = *(const f32x4*)(part + MN + e);
    f32x4 r = *(const f32x4*)(res + e);
    f32x4 bb = *(const f32x4*)(bias + (int)(e % DIM_));
    f32x4 o = a + b + r + bb;
    *(f32x4*)(out + e) = o;
  }
}

// ---------- attention: per (head, seg, 64-row q chunk) ----------
__global__ __launch_bounds__(256) void attn_kernel(
    const unsigned short* __restrict__ Q, const unsigned short* __restrict__ Kb,
    const unsigned short* __restrict__ Vt, unsigned short* __restrict__ O) {
  __shared__ float S[64][512];
  int tid = threadIdx.x;
  int l = tid & 63, w = tid >> 6;
  int orig = blockIdx.x;
  int b = (orig & 7) * (gridDim.x >> 3) + (orig >> 3);
  int qc = b & 7, seg = (b >> 3) & 7, hh = b >> 6;
  int r16 = l & 15, kg = l >> 4, rg = (l >> 4) * 4;
  int qrow0 = seg * SEG_ + qc * 64 + w * 16;
  bf16x8 aq[2];
#pragma unroll
  for (int ks = 0; ks < 2; ++ks)
    aq[ks] = *(const bf16x8*)(Q + (size_t)(qrow0 + r16) * DIM_ + hh * HDIM_ + ks * 32 + kg * 8);
#pragma unroll 4
  for (int kc = 0; kc < 32; ++kc) {
    f32x4 acc = {};
#pragma unroll
    for (int ks = 0; ks < 2; ++ks) {
      bf16x8 bk = *(const bf16x8*)(Kb + (size_t)(seg * SEG_ + kc * 16 + r16) * DIM_ +
                                   hh * HDIM_ + ks * 32 + kg * 8);
      acc = __builtin_amdgcn_mfma_f32_16x16x32_bf16(aq[ks], bk, acc, 0, 0, 0);
    }
#pragma unroll
    for (int j = 0; j < 4; ++j)
      S[w * 16 + rg + j][kc * 16 + r16] = acc[j] * 0.125f;
  }
#pragma unroll 2
  for (int r = 0; r < 16; ++r) {
    float* Sr = &S[w * 16 + r][0];
    f32x4 v0 = *(const f32x4*)(Sr + l * 8);
    f32x4 v1 = *(const f32x4*)(Sr + l * 8 + 4);
    float m = fmaxf(fmaxf(fmaxf(v0[0], v0[1]), fmaxf(v0[2], v0[3])),
                    fmaxf(fmaxf(v1[0], v1[1]), fmaxf(v1[2], v1[3])));
#pragma unroll
    for (int off = 1; off < 64; off <<= 1) m = fmaxf(m, __shfl_xor(m, off));
    float ev[8];
    ev[0] = v0[0]; ev[1] = v0[1]; ev[2] = v0[2]; ev[3] = v0[3];
    ev[4] = v1[0]; ev[5] = v1[1]; ev[6] = v1[2]; ev[7] = v1[3];
    float sum = 0.f;
#pragma unroll
    for (int j = 0; j < 8; ++j) { ev[j] = __expf(ev[j] - m); sum += ev[j]; }
#pragma unroll
    for (int off = 1; off < 64; off <<= 1) sum += __shfl_xor(sum, off);
    float inv = 1.f / sum;
    us8 pk;
#pragma unroll
    for (int j = 0; j < 8; ++j) pk[j] = f2b(ev[j] * inv);
    *(us8*)((unsigned short*)Sr + ((l ^ (r & 7)) * 8)) = pk;
  }
  f32x4 oacc[4] = {};
  const unsigned short* Pr = (const unsigned short*)&S[w * 16 + r16][0];
  int rowx = r16 & 7;
#pragma unroll 2
  for (int ks = 0; ks < 16; ++ks) {
    int chunk = (ks * 4 + kg) ^ rowx;
    bf16x8 pa = *(const bf16x8*)(Pr + chunk * 8);
#pragma unroll
    for (int df = 0; df < 4; ++df) {
      bf16x8 bv = *(const bf16x8*)(Vt + (size_t)(hh * HDIM_ + df * 16 + r16) * SEQ_ +
                                   seg * SEG_ + ks * 32 + kg * 8);
      oacc[df] = __builtin_amdgcn_mfma_f32_16x16x32_bf16(pa, bv, oacc[df], 0, 0, 0);
    }
  }
#pragma unroll
  for (int df = 0; df < 4; ++df)
#pragma unroll
    for (int j = 0; j < 4; ++j)
      O[(size_t)(qrow0 + rg + j) * DIM_ + hh * HDIM_ + df * 16 + r16] = f2b(oacc[df][j]);
}

extern "C" void kernel_launch(void* const* d_in, const int* in_sizes, int n_in,
                              void* d_out, int out_size, void* d_ws, size_t ws_size,
                              hipStream_t stream) {
  (void)in_sizes; (void)n_in; (void)out_size; (void)ws_size;
  const float* hidden = (const float*)d_in[0];
  const float* Wq = (const float*)d_in[2];
  const float* bq = (const float*)d_in[3];
  const float* Wk = (const float*)d_in[4];
  const float* Wv = (const float*)d_in[5];
  const float* bv = (const float*)d_in[6];
  const float* Wo = (const float*)d_in[7];
  const float* bo = (const float*)d_in[8];
  const float* g1 = (const float*)d_in[9];
  const float* b1 = (const float*)d_in[10];
  const float* Wf1 = (const float*)d_in[11];
  const float* bf1 = (const float*)d_in[12];
  const float* Wf2 = (const float*)d_in[13];
  const float* bf2 = (const float*)d_in[14];
  const float* g2 = (const float*)d_in[15];
  const float* b2 = (const float*)d_in[16];

  char* p = (char*)d_ws;
  auto alloc = [&](size_t bytes) {
    char* r = p;
    p += (bytes + 255) & ~(size_t)255;
    return r;
  };
  unsigned short* xln   = (unsigned short*)alloc((size_t)SEQ_ * DIM_ * 2);
  unsigned short* Wqkvt = (unsigned short*)alloc((size_t)DIM_ * QKVN_ * 2);
  unsigned short* Wot   = (unsigned short*)alloc((size_t)DIM_ * DIM_ * 2);
  unsigned short* Wf1t  = (unsigned short*)alloc((size_t)DIM_ * FFN_ * 2);
  unsigned short* Wf2t  = (unsigned short*)alloc((size_t)DIM_ * FFN_ * 2);
  unsigned short* Qb    = (unsigned short*)alloc((size_t)SEQ_ * DIM_ * 2);
  unsigned short* Kbf   = (unsigned short*)alloc((size_t)SEQ_ * DIM_ * 2);
  unsigned short* Vtb   = (unsigned short*)alloc((size_t)SEQ_ * DIM_ * 2);
  unsigned short* attnb = (unsigned short*)alloc((size_t)SEQ_ * DIM_ * 2);
  float*          hbuf  = (float*)alloc((size_t)SEQ_ * DIM_ * 4);
  unsigned short* ybuf  = (unsigned short*)alloc((size_t)SEQ_ * DIM_ * 2);
  unsigned short* gbuf  = (unsigned short*)alloc((size_t)SEQ_ * FFN_ * 2);
  // split-K partials alias Qb..attnb (dead after Wo GEMM): 2*SEQ*DIM f32 == 4*SEQ*DIM bf16
  float* part = (float*)Qb;

  transp_bf16_kernel<<<dim3(DIM_ / 32, DIM_ / 32), 256, 0, stream>>>(Wq, Wqkvt, DIM_, DIM_);
  transp_bf16_kernel<<<dim3(DIM_ / 32, DIM_ / 32), 256, 0, stream>>>(Wk, Wqkvt + (size_t)DIM_ * DIM_, DIM_, DIM_);
  transp_bf16_kernel<<<dim3(DIM_ / 32, DIM_ / 32), 256, 0, stream>>>(Wv, Wqkvt + (size_t)2 * DIM_ * DIM_, DIM_, DIM_);
  transp_bf16_kernel<<<dim3(DIM_ / 32, DIM_ / 32), 256, 0, stream>>>(Wo, Wot, DIM_, DIM_);
  transp_bf16_kernel<<<dim3(FFN_ / 32, DIM_ / 32), 256, 0, stream>>>(Wf1, Wf1t, DIM_, FFN_);
  transp_bf16_kernel<<<dim3(DIM_ / 32, FFN_ / 32), 256, 0, stream>>>(Wf2, Wf2t, FFN_, DIM_);
  ln_kernel<<<SEQ_, 256, 0, stream>>>(hidden, g1, b1, xln);
  // fused QKV projection: N=3840 -> Q, K, V(transposed)
  gemm256_kernel<EPI_QKV><<<dim3(QKVN_ / 256, SEQ_ / 256), 512, 0, stream>>>(
      xln, DIM_, Wqkvt, DIM_, bq, bv, nullptr, Qb, Kbf, Vtb, SEQ_, QKVN_, DIM_);
  attn_kernel<<<NHEAD_ * 8 * 8, 256, 0, stream>>>(Qb, Kbf, Vtb, attnb);
  // output proj + residual -> hbuf (f32)
  gemm256_kernel<EPI_RES><<<dim3(DIM_ / 256, SEQ_ / 256), 512, 0, stream>>>(
      attnb, DIM_, Wot, DIM_, bo, nullptr, hidden, hbuf, nullptr, nullptr, SEQ_, DIM_, DIM_);
  ln_kernel<<<SEQ_, 256, 0, stream>>>(hbuf, g2, b2, ybuf);
  // FFN1 + GELU
  gemm256_kernel<EPI_GELU><<<dim3(FFN_ / 256, SEQ_ / 256), 512, 0, stream>>>(
      ybuf, DIM_, Wf1t, DIM_, bf1, nullptr, nullptr, gbuf, nullptr, nullptr, SEQ_, FFN_, DIM_);
  // FFN2 split-K=2 -> f32 partials, reduce(+bias+residual) -> d_out
  gemm256_kernel<EPI_PART><<<dim3(DIM_ / 256, SEQ_ / 256, 2), 512, 0, stream>>>(
      gbuf, FFN_, Wf2t, FFN_, nullptr, nullptr, nullptr, part, nullptr, nullptr, SEQ_, DIM_, FFN_ / 2);
  reduce_kernel<<<2048, 256, 0, stream>>>(part, bf2, hbuf, (float*)d_out);
}